// Round 6
// baseline (2756.893 us; speedup 1.0000x reference)
//
#include <hip/hip_runtime.h>
#include <math.h>

// Problem constants
#define B_ 8
#define N_ 128
#define H_ 64
#define MH_ 128
#define D_ 4
#define TSTEPS 12
#define NBLK 1024

typedef __attribute__((ext_vector_type(8))) short bf16x8;
typedef __attribute__((ext_vector_type(4))) float f32x4;

__device__ __forceinline__ float fast_tanh(float x) {
    float t = __builtin_amdgcn_exp2f(x * 2.8853900817779268f);
    return 1.0f - 2.0f * __builtin_amdgcn_rcpf(t + 1.0f);
}
__device__ __forceinline__ float fast_sigmoid(float x) {
    float t = __builtin_amdgcn_exp2f(x * -1.4426950408889634f);
    return __builtin_amdgcn_rcpf(1.0f + t);
}
__device__ __forceinline__ unsigned short f2bf(float x) {
    unsigned u = __builtin_bit_cast(unsigned, x);
    u += 0x7fffu + ((u >> 16) & 1u);   // RNE
    return (unsigned short)(u >> 16);
}

// ---------------- workspace layout (float offsets) ----------------
constexpr int OFF_APT = 0;                      // [B][j][i] 131072
constexpr int OFF_P   = OFF_APT + 131072;       // [1024][128] (single buffer)
constexpr int OFF_Q   = OFF_P   + 131072;       // [1024][128] (single buffer)
constexpr int OFF_AGG = OFF_Q   + 131072;       // [1024][64]
constexpr int OFF_WAM = OFF_AGG + 65536;        // [192][64]  WmrT|WmiT|WmnT
constexpr int OFF_WPR = OFF_WAM + 12288;        // [448][64]  Wm1topT|Wm1botT|WhrT|WhiT|WhhT
constexpr int OFF_WO1 = OFF_WPR + 28672;        // [64][64]
constexpr int OFF_WO2 = OFF_WO1 + 4096;         // [64][64]
constexpr int OFF_WO3 = OFF_WO2 + 4096;         // [4][64]
constexpr int OFF_SSE = OFF_WO3 + 256;          // 1 float
constexpr int OFF_CNT = OFF_SSE + 1;            // 1 int (barrier counter, memset per call)

// monotonic-counter grid barrier; requires all NBLK blocks co-resident.
// Bounded spin: if co-residency ever failed, we proceed after ~0.4s instead of
// hanging the queue forever (wrong answer is reported; container stays alive).
__device__ __forceinline__ void grid_barrier(int* cnt, int phase, int tid) {
    __syncthreads();
    if (tid == 0) {
        __builtin_amdgcn_fence(__ATOMIC_RELEASE, "agent");   // drain prior global writes
        __hip_atomic_fetch_add(cnt, 1, __ATOMIC_RELAXED, __HIP_MEMORY_SCOPE_AGENT);
        const int target = phase * NBLK;
        int guard = 0;
        while (__hip_atomic_load(cnt, __ATOMIC_RELAXED, __HIP_MEMORY_SCOPE_AGENT) < target &&
               guard < (1 << 24)) {
            __builtin_amdgcn_s_sleep(1);
            ++guard;
        }
        __builtin_amdgcn_fence(__ATOMIC_ACQUIRE, "agent");   // invalidate L1 for fresh reads
    }
    __syncthreads();
}

__global__ __launch_bounds__(256, 4) void fused(
    const float* __restrict__ A, const float* __restrict__ X,
    const float* __restrict__ Wm1, const float* __restrict__ bm1,
    const float* __restrict__ Wm2, const float* __restrict__ bm2,
    const float* __restrict__ Wir, const float* __restrict__ bir,
    const float* __restrict__ Wii, const float* __restrict__ bii,
    const float* __restrict__ Win, const float* __restrict__ bin_,
    const float* __restrict__ Whr, const float* __restrict__ Whi, const float* __restrict__ Whh,
    const float* __restrict__ Wmr, const float* __restrict__ Wmi, const float* __restrict__ Wmn,
    const float* __restrict__ Wo1, const float* __restrict__ bo1,
    const float* __restrict__ Wo2, const float* __restrict__ bo2,
    const float* __restrict__ Wo3, const float* __restrict__ bo3,
    const float* __restrict__ lsg,
    float* __restrict__ ws, float* __restrict__ out)
{
    // phase-A shared
    __shared__ __align__(16) unsigned short wm2f[8192];   // 16 KB, cached bf16 B-fragments
    __shared__ __align__(16) float Qj[128];
    __shared__ float apRow[128];
    __shared__ float aggbuf[4][64];
    __shared__ float redbuf[2];
    // phase-B shared (blocks 0..255); sH/sHP persist across steps
    __shared__ float sAgg[4][64], sHP[4][192], sH[4][64], sAm[4][192];
    __shared__ float sHn[4][64], sT1[4][64], sT2[4][64];
    __shared__ float sX[4][4], sTgt[4][4], sSq[16];
    __shared__ float sse_blk;

    const int bid = blockIdx.x, tid = threadIdx.x;
    int* cnt = (int*)(ws + OFF_CNT);

    // ================= init phase =================
    {   // adjacency projection: bid = (b, i); writes ApT[b][j][i]
        int b = bid >> 7, i = bid & 127;
        float s = 0.f;
        if (tid < 128) {
            float aij = A[(b * 128 + i) * 128 + tid];
            float aji = A[(b * 128 + tid) * 128 + i];
            s = fast_sigmoid(0.5f * (aij + aji));
            if (tid == i) s = 0.f;
            float r = s;
            #pragma unroll
            for (int d = 1; d < 64; d <<= 1) r += __shfl_xor(r, d);
            if ((tid & 63) == 0) redbuf[tid >> 6] = r;
        }
        __syncthreads();
        if (tid < 128) {
            float tot = redbuf[0] + redbuf[1];
            ws[OFF_APT + (b * 128 + tid) * 128 + i] = s / (tot + 1e-6f);
        }
    }
    {   // weight transposes + state init (grid-strided over 262144 threads)
        int gid = bid * 256 + tid;
        if (gid < 12288) {
            int o = gid >> 6, k = gid & 63;
            const float* src = (o < 64) ? Wmr : (o < 128) ? Wmi : Wmn;
            ws[OFF_WAM + gid] = src[k * 64 + (o & 63)];
        }
        if (gid < 28672) {
            int o = gid >> 6, k = gid & 63;
            float v;
            if (o < 128)      v = Wm1[k * 128 + o];
            else if (o < 256) v = Wm1[(64 + k) * 128 + (o - 128)];
            else {
                int oo = o - 256;
                const float* src = (oo < 64) ? Whr : (oo < 128) ? Whi : Whh;
                v = src[k * 64 + (oo & 63)];
            }
            ws[OFF_WPR + gid] = v;
        }
        if (gid < 4096) {
            int o = gid >> 6, k = gid & 63;
            ws[OFF_WO1 + gid] = Wo1[k * 64 + o];
            ws[OFF_WO2 + gid] = Wo2[k * 64 + o];
        }
        if (gid < 256) {
            int d = gid >> 6, k = gid & 63;
            ws[OFF_WO3 + gid] = Wo3[k * 4 + d];
        }
        if (gid < 131072) {             // P0 = bm1 (h0=0), Q0 = 0
            ws[OFF_P + gid] = bm1[gid & 127];
            ws[OFF_Q + gid] = 0.f;
        }
        if (gid == 0) ws[OFF_SSE] = 0.f;
    }
    // per-block bf16 Wm2 fragment cache in LDS
    for (int idx = tid; idx < 8192; idx += 256) {
        int kt = idx >> 11, nt = (idx >> 9) & 3, ln = (idx >> 3) & 63, e = idx & 7;
        int k = kt * 32 + (ln >> 4) * 8 + e;
        int n = nt * 16 + (ln & 15);
        wm2f[idx] = f2bf(Wm2[k * 64 + n]);
    }
    // phase-B persistent state init
    if (bid < 256) {
        for (int idx = tid; idx < 768; idx += 256) sHP[idx / 192][idx % 192] = 0.f;
        sH[tid >> 6][tid & 63] = 0.f;
        if (tid == 0) sse_blk = 0.f;
    }

    grid_barrier(cnt, 1, tid);

    // ApT row for this block's j (constant across steps)
    if (tid < 128) apRow[tid] = ws[OFF_APT + bid * 128 + tid];

    const int lane = tid & 63, wv = tid >> 6;
    const int l15 = lane & 15, g = lane >> 4;
    const int b = bid >> 7;

    for (int t = 0; t < TSTEPS; ++t) {
        // ================= phase A: message MLP + A-weighted aggregation =================
        {
            if (tid < 128) Qj[tid] = ws[OFF_Q + bid * 128 + tid];
            __syncthreads();

            f32x4 acc[2][4];
            #pragma unroll
            for (int mt = 0; mt < 2; ++mt)
                #pragma unroll
                for (int nt = 0; nt < 4; ++nt) {
                    f32x4 z = {0.f, 0.f, 0.f, 0.f};
                    acc[mt][nt] = z;
                }

            const float* Pb = ws + OFF_P + (b * 128 + wv * 32) * 128;

            #pragma unroll
            for (int kt = 0; kt < 4; ++kt) {
                int k0 = kt * 32 + g * 8;
                bf16x8 bf[4];
                #pragma unroll
                for (int nt = 0; nt < 4; ++nt)
                    bf[nt] = *(const bf16x8*)(&wm2f[((kt * 4 + nt) * 64 + lane) << 3]);
                bf16x8 af[2];
                f32x4 qa = *(const f32x4*)&Qj[k0];
                f32x4 qb = *(const f32x4*)&Qj[k0 + 4];
                #pragma unroll
                for (int mt = 0; mt < 2; ++mt) {
                    const float* p = Pb + (mt * 16 + l15) * 128 + k0;
                    f32x4 pa = *(const f32x4*)p;
                    f32x4 pb = *(const f32x4*)(p + 4);
                    #pragma unroll
                    for (int e = 0; e < 4; ++e) {
                        af[mt][e]     = (short)f2bf(fast_tanh(pa[e] + qa[e]));
                        af[mt][4 + e] = (short)f2bf(fast_tanh(pb[e] + qb[e]));
                    }
                }
                #pragma unroll
                for (int mt = 0; mt < 2; ++mt)
                    #pragma unroll
                    for (int nt = 0; nt < 4; ++nt)
                        acc[mt][nt] = __builtin_amdgcn_mfma_f32_16x16x32_bf16(af[mt], bf[nt], acc[mt][nt], 0, 0, 0);
            }

            float bmv[4];
            #pragma unroll
            for (int nt = 0; nt < 4; ++nt) bmv[nt] = bm2[nt * 16 + l15];
            float pagg[4] = {0.f, 0.f, 0.f, 0.f};
            #pragma unroll
            for (int mt = 0; mt < 2; ++mt) {
                float w[4];
                #pragma unroll
                for (int v = 0; v < 4; ++v) w[v] = apRow[wv * 32 + mt * 16 + g * 4 + v];
                #pragma unroll
                for (int nt = 0; nt < 4; ++nt)
                    #pragma unroll
                    for (int v = 0; v < 4; ++v) {
                        float msg = fast_tanh(acc[mt][nt][v] + bmv[nt]);
                        pagg[nt] += w[v] * msg;
                    }
            }
            #pragma unroll
            for (int nt = 0; nt < 4; ++nt) {
                pagg[nt] += __shfl_xor(pagg[nt], 16);
                pagg[nt] += __shfl_xor(pagg[nt], 32);
            }
            if (lane < 16)
                #pragma unroll
                for (int nt = 0; nt < 4; ++nt) aggbuf[wv][nt * 16 + lane] = pagg[nt];
            __syncthreads();
            if (tid < 64)
                ws[OFF_AGG + bid * 64 + tid] =
                    aggbuf[0][tid] + aggbuf[1][tid] + aggbuf[2][tid] + aggbuf[3][tid];
        }

        grid_barrier(cnt, 2 + 2 * t, tid);

        // ================= phase B: GRU + projections + output MLP (blocks 0..255) =================
        if (bid < 256) {
            const int R0 = bid * 4;
            const int bb = R0 >> 7;
            {
                int r = tid >> 6, o = tid & 63;
                sAgg[r][o] = ws[OFF_AGG + (R0 + r) * 64 + o];
            }
            if (tid < 16) {
                int r = tid >> 2, d = tid & 3;
                int j = (R0 + r) & 127;
                sX[r][d]   = X[((bb * 13 + t) * 128 + j) * 4 + d];
                sTgt[r][d] = X[((bb * 13 + t + 1) * 128 + j) * 4 + d];
            }
            __syncthreads();

            if (tid < 192) {   // am = agg @ [Wmr|Wmi|Wmn]
                const float* w = ws + OFF_WAM + tid * 64;
                float a0 = 0, a1 = 0, a2 = 0, a3 = 0;
                #pragma unroll
                for (int k = 0; k < 64; k += 4) {
                    f32x4 wvv = *(const f32x4*)(w + k);
                    #pragma unroll
                    for (int e = 0; e < 4; ++e) {
                        float ww = wvv[e];
                        a0 += sAgg[0][k + e] * ww; a1 += sAgg[1][k + e] * ww;
                        a2 += sAgg[2][k + e] * ww; a3 += sAgg[3][k + e] * ww;
                    }
                }
                sAm[0][tid] = a0; sAm[1][tid] = a1; sAm[2][tid] = a2; sAm[3][tid] = a3;
            }
            __syncthreads();

            {   // GRU gates; update persistent sH
                int r = tid >> 6, o = tid & 63;
                float xr = bir[o], xi = bii[o], xn = bin_[o];
                #pragma unroll
                for (int d = 0; d < 4; ++d) {
                    float xv = sX[r][d];
                    xr += xv * Wir[d * 64 + o];
                    xi += xv * Wii[d * 64 + o];
                    xn += xv * Win[d * 64 + o];
                }
                float rr = fast_sigmoid(xr + sHP[r][o]       + sAm[r][o]);
                float ig = fast_sigmoid(xi + sHP[r][64 + o]  + sAm[r][64 + o]);
                float nn = fast_tanh  (xn + rr * sHP[r][128 + o] + sAm[r][128 + o]);
                float hn = (1.0f - ig) * nn + ig * sH[r][o];
                sHn[r][o] = hn;
                sH[r][o]  = hn;
            }
            __syncthreads();

            if (t < TSTEPS - 1) {   // next-step projections [P|Q|hr|hi|hh] = h_new @ WprT
                for (int o = tid; o < 448; o += 256) {
                    const float* w = ws + OFF_WPR + o * 64;
                    float a0 = 0, a1 = 0, a2 = 0, a3 = 0;
                    #pragma unroll
                    for (int k = 0; k < 64; k += 4) {
                        f32x4 wvv = *(const f32x4*)(w + k);
                        #pragma unroll
                        for (int e = 0; e < 4; ++e) {
                            float ww = wvv[e];
                            a0 += sHn[0][k + e] * ww; a1 += sHn[1][k + e] * ww;
                            a2 += sHn[2][k + e] * ww; a3 += sHn[3][k + e] * ww;
                        }
                    }
                    float bias = (o < 128) ? bm1[o] : 0.0f;
                    a0 += bias; a1 += bias; a2 += bias; a3 += bias;
                    if (o < 128) {
                        ws[OFF_P + (R0 + 0) * 128 + o] = a0; ws[OFF_P + (R0 + 1) * 128 + o] = a1;
                        ws[OFF_P + (R0 + 2) * 128 + o] = a2; ws[OFF_P + (R0 + 3) * 128 + o] = a3;
                    } else if (o < 256) {
                        int oo = o - 128;
                        ws[OFF_Q + (R0 + 0) * 128 + oo] = a0; ws[OFF_Q + (R0 + 1) * 128 + oo] = a1;
                        ws[OFF_Q + (R0 + 2) * 128 + oo] = a2; ws[OFF_Q + (R0 + 3) * 128 + oo] = a3;
                    } else {
                        int oo = o - 256;
                        sHP[0][oo] = a0; sHP[1][oo] = a1; sHP[2][oo] = a2; sHP[3][oo] = a3;
                    }
                }
            }

            if (tid < 64) {   // output MLP layer 1
                const float* w = ws + OFF_WO1 + tid * 64;
                float a0 = 0, a1 = 0, a2 = 0, a3 = 0;
                #pragma unroll
                for (int k = 0; k < 64; k += 4) {
                    f32x4 wvv = *(const f32x4*)(w + k);
                    #pragma unroll
                    for (int e = 0; e < 4; ++e) {
                        float ww = wvv[e];
                        a0 += sHn[0][k + e] * ww; a1 += sHn[1][k + e] * ww;
                        a2 += sHn[2][k + e] * ww; a3 += sHn[3][k + e] * ww;
                    }
                }
                float bbv = bo1[tid];
                sT1[0][tid] = fmaxf(a0 + bbv, 0.f); sT1[1][tid] = fmaxf(a1 + bbv, 0.f);
                sT1[2][tid] = fmaxf(a2 + bbv, 0.f); sT1[3][tid] = fmaxf(a3 + bbv, 0.f);
            }
            __syncthreads();
            if (tid < 64) {   // layer 2
                const float* w = ws + OFF_WO2 + tid * 64;
                float a0 = 0, a1 = 0, a2 = 0, a3 = 0;
                #pragma unroll
                for (int k = 0; k < 64; k += 4) {
                    f32x4 wvv = *(const f32x4*)(w + k);
                    #pragma unroll
                    for (int e = 0; e < 4; ++e) {
                        float ww = wvv[e];
                        a0 += sT1[0][k + e] * ww; a1 += sT1[1][k + e] * ww;
                        a2 += sT1[2][k + e] * ww; a3 += sT1[3][k + e] * ww;
                    }
                }
                float bbv = bo2[tid];
                sT2[0][tid] = fmaxf(a0 + bbv, 0.f); sT2[1][tid] = fmaxf(a1 + bbv, 0.f);
                sT2[2][tid] = fmaxf(a2 + bbv, 0.f); sT2[3][tid] = fmaxf(a3 + bbv, 0.f);
            }
            __syncthreads();
            if (tid < 16) {   // layer 3 + residual + SSE
                int r = tid >> 2, d = tid & 3;
                const float* w = ws + OFF_WO3 + d * 64;
                float a = 0.f;
                #pragma unroll
                for (int k = 0; k < 64; ++k) a += sT2[r][k] * w[k];
                float p = sX[r][d] + a + bo3[d];
                int j = (R0 + r) & 127;
                out[((bb * TSTEPS + t) * 128 + j) * 4 + d] = p;
                float df = sTgt[r][d] - p;
                sSq[tid] = df * df;
            }
            __syncthreads();
            if (tid == 0) {
                float s = 0.f;
                #pragma unroll
                for (int i2 = 0; i2 < 16; ++i2) s += sSq[i2];
                sse_blk += s;
                if (t == TSTEPS - 1) atomicAdd(ws + OFF_SSE, sse_blk);
            }
        }

        grid_barrier(cnt, 3 + 2 * t, tid);
    }

    // ================= finalize loglik =================
    if (bid == 0 && tid == 0) {
        float sse = __hip_atomic_load(ws + OFF_SSE, __ATOMIC_RELAXED, __HIP_MEMORY_SCOPE_AGENT);
        float ls = lsg[0];
        float sigma = fminf(fmaxf(expf(ls), 1e-4f), 10.0f);
        float c = 0.5f * 4096.0f * logf(2.0f * 3.14159265358979323846f * sigma * sigma);
        float inv2s2 = 1.0f / (2.0f * sigma * sigma);
        out[B_ * TSTEPS * N_ * D_] = -(12.0f * c + sse * inv2s2);
    }
}

extern "C" void kernel_launch(void* const* d_in, const int* in_sizes, int n_in,
                              void* d_out, int out_size, void* d_ws, size_t ws_size,
                              hipStream_t stream)
{
    const float* A    = (const float*)d_in[0];
    const float* X    = (const float*)d_in[1];
    const float* Wm1  = (const float*)d_in[2];
    const float* bm1  = (const float*)d_in[3];
    const float* Wm2  = (const float*)d_in[4];
    const float* bm2  = (const float*)d_in[5];
    const float* Wir  = (const float*)d_in[6];
    const float* bir  = (const float*)d_in[7];
    const float* Wii  = (const float*)d_in[8];
    const float* bii  = (const float*)d_in[9];
    const float* Win  = (const float*)d_in[10];
    const float* bin_ = (const float*)d_in[11];
    const float* Whr  = (const float*)d_in[12];
    const float* Whi  = (const float*)d_in[13];
    const float* Whh  = (const float*)d_in[14];
    const float* Wmr  = (const float*)d_in[15];
    const float* Wmi  = (const float*)d_in[16];
    const float* Wmn  = (const float*)d_in[17];
    const float* Wo1  = (const float*)d_in[18];
    const float* bo1  = (const float*)d_in[19];
    const float* Wo2  = (const float*)d_in[20];
    const float* bo2  = (const float*)d_in[21];
    const float* Wo3  = (const float*)d_in[22];
    const float* bo3  = (const float*)d_in[23];
    const float* lsg  = (const float*)d_in[24];
    float* ws  = (float*)d_ws;
    float* out = (float*)d_out;

    // zero the barrier counter every call (graph-replay safe)
    hipMemsetAsync((char*)d_ws + OFF_CNT * sizeof(float), 0, sizeof(int), stream);

    hipLaunchKernelGGL(fused, dim3(NBLK), dim3(256), 0, stream,
                       A, X, Wm1, bm1, Wm2, bm2, Wir, bir, Wii, bii, Win, bin_,
                       Whr, Whi, Whh, Wmr, Wmi, Wmn, Wo1, bo1, Wo2, bo2, Wo3, bo3,
                       lsg, ws, out);
}

// Round 7
// 569.661 us; speedup vs baseline: 4.8395x; 4.8395x over previous
//
#include <hip/hip_runtime.h>
#include <math.h>

// Problem constants
#define B_ 8
#define N_ 128
#define H_ 64
#define MH_ 128
#define D_ 4
#define TSTEPS 12
#define NBLK 1024

typedef __attribute__((ext_vector_type(8))) short bf16x8;
typedef __attribute__((ext_vector_type(4))) float f32x4;

__device__ __forceinline__ float fast_tanh(float x) {
    float t = __builtin_amdgcn_exp2f(x * 2.8853900817779268f);
    return 1.0f - 2.0f * __builtin_amdgcn_rcpf(t + 1.0f);
}
__device__ __forceinline__ float fast_sigmoid(float x) {
    float t = __builtin_amdgcn_exp2f(x * -1.4426950408889634f);
    return __builtin_amdgcn_rcpf(1.0f + t);
}
__device__ __forceinline__ unsigned short f2bf(float x) {
    unsigned u = __builtin_bit_cast(unsigned, x);
    u += 0x7fffu + ((u >> 16) & 1u);   // RNE
    return (unsigned short)(u >> 16);
}

// ---------------- workspace layout (float offsets) ----------------
// P double-buffered: written by block (b,j) in phase B while other blocks of
// batch b still read it in phase A -> cur/next toggle per step.
// Q/H/HP are block-private (only block (b,j) reads+writes its row) -> single.
constexpr int OFF_APT = 0;                      // [B][j][i] 131072
constexpr int OFF_P0  = OFF_APT + 131072;       // [1024][128]
constexpr int OFF_P1  = OFF_P0  + 131072;       // [1024][128]
constexpr int OFF_Q   = OFF_P1  + 131072;       // [1024][128]
constexpr int OFF_H   = OFF_Q   + 131072;       // [1024][64]
constexpr int OFF_HP  = OFF_H   + 65536;        // [1024][192] (hr|hi|hh)
constexpr int OFF_WAM = OFF_HP  + 196608;       // [192][64]  WmrT|WmiT|WmnT
constexpr int OFF_WPR = OFF_WAM + 12288;        // [448][64]  Wm1topT|Wm1botT|WhrT|WhiT|WhhT
constexpr int OFF_WO1 = OFF_WPR + 28672;        // [64][64]
constexpr int OFF_WO2 = OFF_WO1 + 4096;         // [64][64]
constexpr int OFF_WO3 = OFF_WO2 + 4096;         // [4][64]
constexpr int OFF_SSE = OFF_WO3 + 256;          // 1 float (zeroed by pre)
constexpr int OFF_DONE= OFF_SSE + 1;            // 1 int   (zeroed by pre)

// ---------------- pre: adjacency + weight transposes + state init ----------------
__global__ __launch_bounds__(256) void pre(
    const float* __restrict__ A,
    const float* __restrict__ Wm1, const float* __restrict__ bm1,
    const float* __restrict__ Whr, const float* __restrict__ Whi, const float* __restrict__ Whh,
    const float* __restrict__ Wmr, const float* __restrict__ Wmi, const float* __restrict__ Wmn,
    const float* __restrict__ Wo1, const float* __restrict__ Wo2, const float* __restrict__ Wo3,
    float* __restrict__ ws)
{
    const int bid = blockIdx.x, tid = threadIdx.x;
    __shared__ float redbuf[2];
    {   // adjacency projection: bid = (b, i); writes ApT[b][j][i]
        int b = bid >> 7, i = bid & 127;
        float s = 0.f;
        if (tid < 128) {
            float aij = A[(b * 128 + i) * 128 + tid];
            float aji = A[(b * 128 + tid) * 128 + i];
            s = fast_sigmoid(0.5f * (aij + aji));
            if (tid == i) s = 0.f;
            float r = s;
            #pragma unroll
            for (int d = 1; d < 64; d <<= 1) r += __shfl_xor(r, d);
            if ((tid & 63) == 0) redbuf[tid >> 6] = r;
        }
        __syncthreads();
        if (tid < 128) {
            float tot = redbuf[0] + redbuf[1];
            ws[OFF_APT + (b * 128 + tid) * 128 + i] = s / (tot + 1e-6f);
        }
    }
    int gid = bid * 256 + tid;
    if (gid < 12288) {
        int o = gid >> 6, k = gid & 63;
        const float* src = (o < 64) ? Wmr : (o < 128) ? Wmi : Wmn;
        ws[OFF_WAM + gid] = src[k * 64 + (o & 63)];
    }
    if (gid < 28672) {
        int o = gid >> 6, k = gid & 63;
        float v;
        if (o < 128)      v = Wm1[k * 128 + o];
        else if (o < 256) v = Wm1[(64 + k) * 128 + (o - 128)];
        else {
            int oo = o - 256;
            const float* src = (oo < 64) ? Whr : (oo < 128) ? Whi : Whh;
            v = src[k * 64 + (oo & 63)];
        }
        ws[OFF_WPR + gid] = v;
    }
    if (gid < 4096) {
        int o = gid >> 6, k = gid & 63;
        ws[OFF_WO1 + gid] = Wo1[k * 64 + o];
        ws[OFF_WO2 + gid] = Wo2[k * 64 + o];
    }
    if (gid < 256) {
        int d = gid >> 6, k = gid & 63;
        ws[OFF_WO3 + gid] = Wo3[k * 4 + d];
    }
    if (gid < 131072) {             // P0 = bm1 (h0=0), Q0 = 0
        ws[OFF_P0 + gid] = bm1[gid & 127];
        ws[OFF_Q  + gid] = 0.f;
    }
    if (gid < 65536)  ws[OFF_H  + gid] = 0.f;
    if (gid < 196608) ws[OFF_HP + gid] = 0.f;
    if (gid == 0) { ws[OFF_SSE] = 0.f; *(int*)(ws + OFF_DONE) = 0; }
}

// ---------------- per-step fused kernel: message MLP + row-local GRU/proj/MLP ----------------
// block = (b, j); phase A: 4 waves over i; phase B: row j only (block-private state)
__global__ __launch_bounds__(256) void step(
    const float* __restrict__ X,
    const float* __restrict__ Wm2, const float* __restrict__ bm2,
    const float* __restrict__ Wir, const float* __restrict__ bir,
    const float* __restrict__ Wii, const float* __restrict__ bii,
    const float* __restrict__ Win, const float* __restrict__ bin_,
    const float* __restrict__ bm1,
    const float* __restrict__ bo1, const float* __restrict__ bo2, const float* __restrict__ bo3,
    const float* __restrict__ lsg,
    float* __restrict__ ws,
    const float* __restrict__ Pc, float* __restrict__ Pn,
    float* __restrict__ out, int t)
{
    const int bid = blockIdx.x, tid = threadIdx.x;
    const int b = bid >> 7, j = bid & 127;
    const int lane = tid & 63, wv = tid >> 6;
    const int l15 = lane & 15, g = lane >> 4;

    __shared__ __align__(16) unsigned short wm2f[8192];
    __shared__ __align__(16) float Qj[128];
    __shared__ float apRow[128];
    __shared__ float aggbuf[4][64];
    __shared__ float sAgg[64], sAm[192], sH[64], sHn[64];
    __shared__ float sT1[64], sT2[64], sX[4], sTgt[4], sSq[4];

    // stage Wm2 fragments + Q row + Ap row
    for (int idx = tid; idx < 8192; idx += 256) {
        int kt = idx >> 11, nt = (idx >> 9) & 3, ln = (idx >> 3) & 63, e = idx & 7;
        int k = kt * 32 + (ln >> 4) * 8 + e;
        int n = nt * 16 + (ln & 15);
        wm2f[idx] = f2bf(Wm2[k * 64 + n]);
    }
    if (tid < 128) {
        Qj[tid]    = ws[OFF_Q + bid * 128 + tid];
        apRow[tid] = ws[OFF_APT + bid * 128 + tid];
    }
    if (tid < 4) {
        sX[tid]   = X[((b * 13 + t) * 128 + j) * 4 + tid];
        sTgt[tid] = X[((b * 13 + t + 1) * 128 + j) * 4 + tid];
    }
    if (tid < 64) sH[tid] = ws[OFF_H + bid * 64 + tid];
    __syncthreads();

    // ===== phase A: msg = tanh(tanh(P_i + Q_j) @ Wm2 + bm2), agg = Ap-weighted sum over i =====
    f32x4 acc[2][4];
    #pragma unroll
    for (int mt = 0; mt < 2; ++mt)
        #pragma unroll
        for (int nt = 0; nt < 4; ++nt) {
            f32x4 z = {0.f, 0.f, 0.f, 0.f};
            acc[mt][nt] = z;
        }
    const float* Pb = Pc + (b * 128 + wv * 32) * 128;
    #pragma unroll
    for (int kt = 0; kt < 4; ++kt) {
        int k0 = kt * 32 + g * 8;
        bf16x8 bf[4];
        #pragma unroll
        for (int nt = 0; nt < 4; ++nt)
            bf[nt] = *(const bf16x8*)(&wm2f[((kt * 4 + nt) * 64 + lane) << 3]);
        bf16x8 af[2];
        f32x4 qa = *(const f32x4*)&Qj[k0];
        f32x4 qb = *(const f32x4*)&Qj[k0 + 4];
        #pragma unroll
        for (int mt = 0; mt < 2; ++mt) {
            const float* p = Pb + (mt * 16 + l15) * 128 + k0;
            f32x4 pa = *(const f32x4*)p;
            f32x4 pb = *(const f32x4*)(p + 4);
            #pragma unroll
            for (int e = 0; e < 4; ++e) {
                af[mt][e]     = (short)f2bf(fast_tanh(pa[e] + qa[e]));
                af[mt][4 + e] = (short)f2bf(fast_tanh(pb[e] + qb[e]));
            }
        }
        #pragma unroll
        for (int mt = 0; mt < 2; ++mt)
            #pragma unroll
            for (int nt = 0; nt < 4; ++nt)
                acc[mt][nt] = __builtin_amdgcn_mfma_f32_16x16x32_bf16(af[mt], bf[nt], acc[mt][nt], 0, 0, 0);
    }
    {
        float bmv[4];
        #pragma unroll
        for (int nt = 0; nt < 4; ++nt) bmv[nt] = bm2[nt * 16 + l15];
        float pagg[4] = {0.f, 0.f, 0.f, 0.f};
        #pragma unroll
        for (int mt = 0; mt < 2; ++mt) {
            float w[4];
            #pragma unroll
            for (int v = 0; v < 4; ++v) w[v] = apRow[wv * 32 + mt * 16 + g * 4 + v];
            #pragma unroll
            for (int nt = 0; nt < 4; ++nt)
                #pragma unroll
                for (int v = 0; v < 4; ++v) {
                    float msg = fast_tanh(acc[mt][nt][v] + bmv[nt]);
                    pagg[nt] += w[v] * msg;
                }
        }
        #pragma unroll
        for (int nt = 0; nt < 4; ++nt) {
            pagg[nt] += __shfl_xor(pagg[nt], 16);
            pagg[nt] += __shfl_xor(pagg[nt], 32);
        }
        if (lane < 16)
            #pragma unroll
            for (int nt = 0; nt < 4; ++nt) aggbuf[wv][nt * 16 + lane] = pagg[nt];
    }
    __syncthreads();
    if (tid < 64)
        sAgg[tid] = aggbuf[0][tid] + aggbuf[1][tid] + aggbuf[2][tid] + aggbuf[3][tid];
    __syncthreads();

    // ===== phase B: row-local =====
    // am = agg @ [Wmr|Wmi|Wmn]
    if (tid < 192) {
        const float* w = ws + OFF_WAM + tid * 64;
        float a = 0.f;
        #pragma unroll
        for (int k = 0; k < 64; k += 4) {
            f32x4 wv4 = *(const f32x4*)(w + k);
            a += sAgg[k] * wv4[0] + sAgg[k+1] * wv4[1] + sAgg[k+2] * wv4[2] + sAgg[k+3] * wv4[3];
        }
        sAm[tid] = a;
    }
    __syncthreads();

    // GRU gates
    if (tid < 64) {
        int o = tid;
        float xr = bir[o], xi = bii[o], xn = bin_[o];
        #pragma unroll
        for (int d = 0; d < 4; ++d) {
            float xv = sX[d];
            xr += xv * Wir[d * 64 + o];
            xi += xv * Wii[d * 64 + o];
            xn += xv * Win[d * 64 + o];
        }
        float hpr = ws[OFF_HP + bid * 192 + o];
        float hpi = ws[OFF_HP + bid * 192 + 64 + o];
        float hpn = ws[OFF_HP + bid * 192 + 128 + o];
        float rr = fast_sigmoid(xr + hpr + sAm[o]);
        float ig = fast_sigmoid(xi + hpi + sAm[64 + o]);
        float nn = fast_tanh  (xn + rr * hpn + sAm[128 + o]);
        float hn = (1.0f - ig) * nn + ig * sH[o];
        sHn[o] = hn;
        ws[OFF_H + bid * 64 + o] = hn;
    }
    __syncthreads();

    // next-step projections: [P|Q|hr|hi|hh] = h_new @ WprT (P into the NEXT buffer)
    if (t < TSTEPS - 1) {
        for (int o = tid; o < 448; o += 256) {
            const float* w = ws + OFF_WPR + o * 64;
            float a = (o < 128) ? bm1[o] : 0.f;
            #pragma unroll
            for (int k = 0; k < 64; k += 4) {
                f32x4 wv4 = *(const f32x4*)(w + k);
                a += sHn[k] * wv4[0] + sHn[k+1] * wv4[1] + sHn[k+2] * wv4[2] + sHn[k+3] * wv4[3];
            }
            if (o < 128)      Pn[bid * 128 + o] = a;
            else if (o < 256) ws[OFF_Q + bid * 128 + (o - 128)] = a;
            else              ws[OFF_HP + bid * 192 + (o - 256)] = a;
        }
    }

    // output MLP
    if (tid < 64) {
        const float* w = ws + OFF_WO1 + tid * 64;
        float a = bo1[tid];
        #pragma unroll
        for (int k = 0; k < 64; k += 4) {
            f32x4 wv4 = *(const f32x4*)(w + k);
            a += sHn[k] * wv4[0] + sHn[k+1] * wv4[1] + sHn[k+2] * wv4[2] + sHn[k+3] * wv4[3];
        }
        sT1[tid] = fmaxf(a, 0.f);
    }
    __syncthreads();
    if (tid < 64) {
        const float* w = ws + OFF_WO2 + tid * 64;
        float a = bo2[tid];
        #pragma unroll
        for (int k = 0; k < 64; k += 4) {
            f32x4 wv4 = *(const f32x4*)(w + k);
            a += sT1[k] * wv4[0] + sT1[k+1] * wv4[1] + sT1[k+2] * wv4[2] + sT1[k+3] * wv4[3];
        }
        sT2[tid] = fmaxf(a, 0.f);
    }
    __syncthreads();
    if (tid < 4) {
        const float* w = ws + OFF_WO3 + tid * 64;
        float a = 0.f;
        #pragma unroll
        for (int k = 0; k < 64; ++k) a += sT2[k] * w[k];
        float p = sX[tid] + a + bo3[tid];
        out[((b * TSTEPS + t) * 128 + j) * 4 + tid] = p;
        float df = sTgt[tid] - p;
        sSq[tid] = df * df;
    }
    __syncthreads();
    if (tid == 0) {
        atomicAdd(ws + OFF_SSE, sSq[0] + sSq[1] + sSq[2] + sSq[3]);
        if (t == TSTEPS - 1) {
            // last-arriver finalizes loglik (acq_rel on done syncs with all SSE adds)
            int prev = __hip_atomic_fetch_add((int*)(ws + OFF_DONE), 1,
                                              __ATOMIC_ACQ_REL, __HIP_MEMORY_SCOPE_AGENT);
            if (prev == NBLK - 1) {
                float sse = __hip_atomic_load(ws + OFF_SSE, __ATOMIC_RELAXED, __HIP_MEMORY_SCOPE_AGENT);
                float ls = lsg[0];
                float sigma = fminf(fmaxf(expf(ls), 1e-4f), 10.0f);
                float c = 0.5f * 4096.0f * logf(2.0f * 3.14159265358979323846f * sigma * sigma);
                float inv2s2 = 1.0f / (2.0f * sigma * sigma);
                out[B_ * TSTEPS * N_ * D_] = -(12.0f * c + sse * inv2s2);
            }
        }
    }
}

extern "C" void kernel_launch(void* const* d_in, const int* in_sizes, int n_in,
                              void* d_out, int out_size, void* d_ws, size_t ws_size,
                              hipStream_t stream)
{
    const float* A    = (const float*)d_in[0];
    const float* X    = (const float*)d_in[1];
    const float* Wm1  = (const float*)d_in[2];
    const float* bm1  = (const float*)d_in[3];
    const float* Wm2  = (const float*)d_in[4];
    const float* bm2  = (const float*)d_in[5];
    const float* Wir  = (const float*)d_in[6];
    const float* bir  = (const float*)d_in[7];
    const float* Wii  = (const float*)d_in[8];
    const float* bii  = (const float*)d_in[9];
    const float* Win  = (const float*)d_in[10];
    const float* bin_ = (const float*)d_in[11];
    const float* Whr  = (const float*)d_in[12];
    const float* Whi  = (const float*)d_in[13];
    const float* Whh  = (const float*)d_in[14];
    const float* Wmr  = (const float*)d_in[15];
    const float* Wmi  = (const float*)d_in[16];
    const float* Wmn  = (const float*)d_in[17];
    const float* Wo1  = (const float*)d_in[18];
    const float* bo1  = (const float*)d_in[19];
    const float* Wo2  = (const float*)d_in[20];
    const float* bo2  = (const float*)d_in[21];
    const float* Wo3  = (const float*)d_in[22];
    const float* bo3  = (const float*)d_in[23];
    const float* lsg  = (const float*)d_in[24];
    float* ws  = (float*)d_ws;
    float* out = (float*)d_out;

    hipLaunchKernelGGL(pre, dim3(NBLK), dim3(256), 0, stream,
                       A, Wm1, bm1, Whr, Whi, Whh, Wmr, Wmi, Wmn, Wo1, Wo2, Wo3, ws);

    for (int t = 0; t < TSTEPS; ++t) {
        const float* Pc = ws + ((t & 1) ? OFF_P1 : OFF_P0);
        float*       Pn = ws + ((t & 1) ? OFF_P0 : OFF_P1);
        hipLaunchKernelGGL(step, dim3(NBLK), dim3(256), 0, stream,
                           X, Wm2, bm2, Wir, bir, Wii, bii, Win, bin_, bm1,
                           bo1, bo2, bo3, lsg, ws, Pc, Pn, out, t);
    }
}

// Round 8
// 515.704 us; speedup vs baseline: 5.3459x; 1.1046x over previous
//
#include <hip/hip_runtime.h>
#include <math.h>

// Problem constants
#define B_ 8
#define N_ 128
#define H_ 64
#define MH_ 128
#define D_ 4
#define TSTEPS 12
#define NBLK 1024

typedef __attribute__((ext_vector_type(8))) short bf16x8;
typedef __attribute__((ext_vector_type(4))) float f32x4;

__device__ __forceinline__ float fast_tanh(float x) {
    float t = __builtin_amdgcn_exp2f(x * 2.8853900817779268f);
    return 1.0f - 2.0f * __builtin_amdgcn_rcpf(t + 1.0f);
}
__device__ __forceinline__ float fast_sigmoid(float x) {
    float t = __builtin_amdgcn_exp2f(x * -1.4426950408889634f);
    return __builtin_amdgcn_rcpf(1.0f + t);
}
__device__ __forceinline__ unsigned short f2bf(float x) {
    unsigned u = __builtin_bit_cast(unsigned, x);
    u += 0x7fffu + ((u >> 16) & 1u);   // RNE
    return (unsigned short)(u >> 16);
}

// ---------------- workspace layout (float offsets) ----------------
// P double-buffered (cross-block read); Q/H/HP block-private -> single.
constexpr int OFF_APT = 0;                      // [B][j][i] 131072
constexpr int OFF_P0  = OFF_APT + 131072;       // [1024][128]
constexpr int OFF_P1  = OFF_P0  + 131072;       // [1024][128]
constexpr int OFF_Q   = OFF_P1  + 131072;       // [1024][128]
constexpr int OFF_H   = OFF_Q   + 131072;       // [1024][64]
constexpr int OFF_HP  = OFF_H   + 65536;        // [1024][192] (hr|hi|hh)
constexpr int OFF_WAM = OFF_HP  + 196608;       // [192][64]  WmrT|WmiT|WmnT
constexpr int OFF_WPR = OFF_WAM + 12288;        // [448][64]  Wm1topT|Wm1botT|WhrT|WhiT|WhhT
constexpr int OFF_WO1 = OFF_WPR + 28672;        // [64][64]
constexpr int OFF_WO2 = OFF_WO1 + 4096;         // [64][64]
constexpr int OFF_WO3 = OFF_WO2 + 4096;         // [4][64]
constexpr int OFF_WM2F= OFF_WO3 + 256;          // 8192 ushorts (bf16 B-fragments, packed once)
constexpr int OFF_SSE = OFF_WM2F + 4096;        // 1 float (zeroed by pre)
constexpr int OFF_DONE= OFF_SSE + 1;            // 1 int   (zeroed by pre)

// ---------------- pre: adjacency + weight transposes + Wm2 pack + state init ----------------
__global__ __launch_bounds__(256) void pre(
    const float* __restrict__ A,
    const float* __restrict__ Wm1, const float* __restrict__ bm1,
    const float* __restrict__ Wm2,
    const float* __restrict__ Whr, const float* __restrict__ Whi, const float* __restrict__ Whh,
    const float* __restrict__ Wmr, const float* __restrict__ Wmi, const float* __restrict__ Wmn,
    const float* __restrict__ Wo1, const float* __restrict__ Wo2, const float* __restrict__ Wo3,
    float* __restrict__ ws)
{
    const int bid = blockIdx.x, tid = threadIdx.x;
    __shared__ float redbuf[2];
    {   // adjacency projection: bid = (b, i); writes ApT[b][j][i]
        int b = bid >> 7, i = bid & 127;
        float s = 0.f;
        if (tid < 128) {
            float aij = A[(b * 128 + i) * 128 + tid];
            float aji = A[(b * 128 + tid) * 128 + i];
            s = fast_sigmoid(0.5f * (aij + aji));
            if (tid == i) s = 0.f;
            float r = s;
            #pragma unroll
            for (int d = 1; d < 64; d <<= 1) r += __shfl_xor(r, d);
            if ((tid & 63) == 0) redbuf[tid >> 6] = r;
        }
        __syncthreads();
        if (tid < 128) {
            float tot = redbuf[0] + redbuf[1];
            ws[OFF_APT + (b * 128 + tid) * 128 + i] = s / (tot + 1e-6f);
        }
    }
    int gid = bid * 256 + tid;
    if (gid < 12288) {
        int o = gid >> 6, k = gid & 63;
        const float* src = (o < 64) ? Wmr : (o < 128) ? Wmi : Wmn;
        ws[OFF_WAM + gid] = src[k * 64 + (o & 63)];
    }
    if (gid < 28672) {
        int o = gid >> 6, k = gid & 63;
        float v;
        if (o < 128)      v = Wm1[k * 128 + o];
        else if (o < 256) v = Wm1[(64 + k) * 128 + (o - 128)];
        else {
            int oo = o - 256;
            const float* src = (oo < 64) ? Whr : (oo < 128) ? Whi : Whh;
            v = src[k * 64 + (oo & 63)];
        }
        ws[OFF_WPR + gid] = v;
    }
    if (gid < 4096) {
        int o = gid >> 6, k = gid & 63;
        ws[OFF_WO1 + gid] = Wo1[k * 64 + o];
        ws[OFF_WO2 + gid] = Wo2[k * 64 + o];
    }
    if (gid < 256) {
        int d = gid >> 6, k = gid & 63;
        ws[OFF_WO3 + gid] = Wo3[k * 4 + d];
    }
    if (gid < 8192) {   // pack Wm2 into bf16 MFMA B-fragments (once per call)
        int kt = gid >> 11, nt = (gid >> 9) & 3, ln = (gid >> 3) & 63, e = gid & 7;
        int k = kt * 32 + (ln >> 4) * 8 + e;
        int n = nt * 16 + (ln & 15);
        ((unsigned short*)(ws + OFF_WM2F))[gid] = f2bf(Wm2[k * 64 + n]);
    }
    if (gid < 131072) {             // P0 = bm1 (h0=0), Q0 = 0
        ws[OFF_P0 + gid] = bm1[gid & 127];
        ws[OFF_Q  + gid] = 0.f;
    }
    if (gid < 65536)  ws[OFF_H  + gid] = 0.f;
    if (gid < 196608) ws[OFF_HP + gid] = 0.f;
    if (gid == 0) { ws[OFF_SSE] = 0.f; *(int*)(ws + OFF_DONE) = 0; }
}

// ---------------- per-step fused kernel: message MLP + row-local GRU/proj/MLP ----------------
// block = (b, j); phase A: 4 waves over i; phase B: row j only (block-private state)
__global__ __launch_bounds__(256) void step(
    const float* __restrict__ X,
    const float* __restrict__ bm2,
    const float* __restrict__ Wir, const float* __restrict__ bir,
    const float* __restrict__ Wii, const float* __restrict__ bii,
    const float* __restrict__ Win, const float* __restrict__ bin_,
    const float* __restrict__ bm1,
    const float* __restrict__ bo1, const float* __restrict__ bo2, const float* __restrict__ bo3,
    const float* __restrict__ lsg,
    float* __restrict__ ws,
    const float* __restrict__ Pc, float* __restrict__ Pn,
    float* __restrict__ out, int t)
{
    const int bid = blockIdx.x, tid = threadIdx.x;
    const int b = bid >> 7, j = bid & 127;
    const int lane = tid & 63, wv = tid >> 6;
    const int l15 = lane & 15, g = lane >> 4;

    __shared__ __align__(16) float Qj[128];
    __shared__ float apRow[128];
    __shared__ float aggbuf[4][64];
    __shared__ float sAgg[64], sAm[192], sH[64], sHn[64];
    __shared__ float sT1[64], sT2[64], sX[4], sTgt[4], sSq[4];

    if (tid < 128) {
        Qj[tid]    = ws[OFF_Q + bid * 128 + tid];
        apRow[tid] = ws[OFF_APT + bid * 128 + tid];
    }
    if (tid < 4) {
        sX[tid]   = X[((b * 13 + t) * 128 + j) * 4 + tid];
        sTgt[tid] = X[((b * 13 + t + 1) * 128 + j) * 4 + tid];
    }
    if (tid < 64) sH[tid] = ws[OFF_H + bid * 64 + tid];
    __syncthreads();

    // ===== phase A: msg = tanh(tanh(P_i + Q_j) @ Wm2 + bm2), agg = Ap-weighted sum over i =====
    const unsigned short* wm2f = (const unsigned short*)(ws + OFF_WM2F);
    f32x4 acc[2][4];
    #pragma unroll
    for (int mt = 0; mt < 2; ++mt)
        #pragma unroll
        for (int nt = 0; nt < 4; ++nt) {
            f32x4 z = {0.f, 0.f, 0.f, 0.f};
            acc[mt][nt] = z;
        }
    const float* Pb = Pc + (b * 128 + wv * 32) * 128;
    #pragma unroll
    for (int kt = 0; kt < 4; ++kt) {
        int k0 = kt * 32 + g * 8;
        bf16x8 bf[4];
        #pragma unroll
        for (int nt = 0; nt < 4; ++nt)
            bf[nt] = *(const bf16x8*)(wm2f + (((kt * 4 + nt) * 64 + lane) << 3));
        bf16x8 af[2];
        f32x4 qa = *(const f32x4*)&Qj[k0];
        f32x4 qb = *(const f32x4*)&Qj[k0 + 4];
        #pragma unroll
        for (int mt = 0; mt < 2; ++mt) {
            const float* p = Pb + (mt * 16 + l15) * 128 + k0;
            f32x4 pa = *(const f32x4*)p;
            f32x4 pb = *(const f32x4*)(p + 4);
            #pragma unroll
            for (int e = 0; e < 4; ++e) {
                af[mt][e]     = (short)f2bf(fast_tanh(pa[e] + qa[e]));
                af[mt][4 + e] = (short)f2bf(fast_tanh(pb[e] + qb[e]));
            }
        }
        #pragma unroll
        for (int mt = 0; mt < 2; ++mt)
            #pragma unroll
            for (int nt = 0; nt < 4; ++nt)
                acc[mt][nt] = __builtin_amdgcn_mfma_f32_16x16x32_bf16(af[mt], bf[nt], acc[mt][nt], 0, 0, 0);
    }
    {
        float bmv[4];
        #pragma unroll
        for (int nt = 0; nt < 4; ++nt) bmv[nt] = bm2[nt * 16 + l15];
        float pagg[4] = {0.f, 0.f, 0.f, 0.f};
        #pragma unroll
        for (int mt = 0; mt < 2; ++mt) {
            float w[4];
            #pragma unroll
            for (int v = 0; v < 4; ++v) w[v] = apRow[wv * 32 + mt * 16 + g * 4 + v];
            #pragma unroll
            for (int nt = 0; nt < 4; ++nt)
                #pragma unroll
                for (int v = 0; v < 4; ++v) {
                    float msg = fast_tanh(acc[mt][nt][v] + bmv[nt]);
                    pagg[nt] += w[v] * msg;
                }
        }
        #pragma unroll
        for (int nt = 0; nt < 4; ++nt) {
            pagg[nt] += __shfl_xor(pagg[nt], 16);
            pagg[nt] += __shfl_xor(pagg[nt], 32);
        }
        if (lane < 16)
            #pragma unroll
            for (int nt = 0; nt < 4; ++nt) aggbuf[wv][nt * 16 + lane] = pagg[nt];
    }
    __syncthreads();
    if (tid < 64)
        sAgg[tid] = aggbuf[0][tid] + aggbuf[1][tid] + aggbuf[2][tid] + aggbuf[3][tid];
    __syncthreads();

    // ===== phase B: row-local =====
    // am = agg @ [Wmr|Wmi|Wmn]
    if (tid < 192) {
        const float* w = ws + OFF_WAM + tid * 64;
        float a = 0.f;
        #pragma unroll
        for (int k = 0; k < 64; k += 4) {
            f32x4 wv4 = *(const f32x4*)(w + k);
            a += sAgg[k] * wv4[0] + sAgg[k+1] * wv4[1] + sAgg[k+2] * wv4[2] + sAgg[k+3] * wv4[3];
        }
        sAm[tid] = a;
    }
    __syncthreads();

    // GRU gates
    if (tid < 64) {
        int o = tid;
        float xr = bir[o], xi = bii[o], xn = bin_[o];
        #pragma unroll
        for (int d = 0; d < 4; ++d) {
            float xv = sX[d];
            xr += xv * Wir[d * 64 + o];
            xi += xv * Wii[d * 64 + o];
            xn += xv * Win[d * 64 + o];
        }
        float hpr = ws[OFF_HP + bid * 192 + o];
        float hpi = ws[OFF_HP + bid * 192 + 64 + o];
        float hpn = ws[OFF_HP + bid * 192 + 128 + o];
        float rr = fast_sigmoid(xr + hpr + sAm[o]);
        float ig = fast_sigmoid(xi + hpi + sAm[64 + o]);
        float nn = fast_tanh  (xn + rr * hpn + sAm[128 + o]);
        float hn = (1.0f - ig) * nn + ig * sH[o];
        sHn[o] = hn;
        ws[OFF_H + bid * 64 + o] = hn;
    }
    __syncthreads();

    // next-step projections: [P|Q|hr|hi|hh] = h_new @ WprT (P into the NEXT buffer)
    if (t < TSTEPS - 1) {
        for (int o = tid; o < 448; o += 256) {
            const float* w = ws + OFF_WPR + o * 64;
            float a = (o < 128) ? bm1[o] : 0.f;
            #pragma unroll
            for (int k = 0; k < 64; k += 4) {
                f32x4 wv4 = *(const f32x4*)(w + k);
                a += sHn[k] * wv4[0] + sHn[k+1] * wv4[1] + sHn[k+2] * wv4[2] + sHn[k+3] * wv4[3];
            }
            if (o < 128)      Pn[bid * 128 + o] = a;
            else if (o < 256) ws[OFF_Q + bid * 128 + (o - 128)] = a;
            else              ws[OFF_HP + bid * 192 + (o - 256)] = a;
        }
    }

    // output MLP
    if (tid < 64) {
        const float* w = ws + OFF_WO1 + tid * 64;
        float a = bo1[tid];
        #pragma unroll
        for (int k = 0; k < 64; k += 4) {
            f32x4 wv4 = *(const f32x4*)(w + k);
            a += sHn[k] * wv4[0] + sHn[k+1] * wv4[1] + sHn[k+2] * wv4[2] + sHn[k+3] * wv4[3];
        }
        sT1[tid] = fmaxf(a, 0.f);
    }
    __syncthreads();
    if (tid < 64) {
        const float* w = ws + OFF_WO2 + tid * 64;
        float a = bo2[tid];
        #pragma unroll
        for (int k = 0; k < 64; k += 4) {
            f32x4 wv4 = *(const f32x4*)(w + k);
            a += sT1[k] * wv4[0] + sT1[k+1] * wv4[1] + sT1[k+2] * wv4[2] + sT1[k+3] * wv4[3];
        }
        sT2[tid] = fmaxf(a, 0.f);
    }
    __syncthreads();
    if (tid < 4) {
        const float* w = ws + OFF_WO3 + tid * 64;
        float a = 0.f;
        #pragma unroll
        for (int k = 0; k < 64; ++k) a += sT2[k] * w[k];
        float p = sX[tid] + a + bo3[tid];
        out[((b * TSTEPS + t) * 128 + j) * 4 + tid] = p;
        float df = sTgt[tid] - p;
        sSq[tid] = df * df;
    }
    __syncthreads();
    if (tid == 0) {
        atomicAdd(ws + OFF_SSE, sSq[0] + sSq[1] + sSq[2] + sSq[3]);
        if (t == TSTEPS - 1) {
            // last-arriver finalizes loglik (acq_rel on done syncs with all SSE adds)
            int prev = __hip_atomic_fetch_add((int*)(ws + OFF_DONE), 1,
                                              __ATOMIC_ACQ_REL, __HIP_MEMORY_SCOPE_AGENT);
            if (prev == NBLK - 1) {
                float sse = __hip_atomic_load(ws + OFF_SSE, __ATOMIC_RELAXED, __HIP_MEMORY_SCOPE_AGENT);
                float ls = lsg[0];
                float sigma = fminf(fmaxf(expf(ls), 1e-4f), 10.0f);
                float c = 0.5f * 4096.0f * logf(2.0f * 3.14159265358979323846f * sigma * sigma);
                float inv2s2 = 1.0f / (2.0f * sigma * sigma);
                out[B_ * TSTEPS * N_ * D_] = -(12.0f * c + sse * inv2s2);
            }
        }
    }
}

extern "C" void kernel_launch(void* const* d_in, const int* in_sizes, int n_in,
                              void* d_out, int out_size, void* d_ws, size_t ws_size,
                              hipStream_t stream)
{
    const float* A    = (const float*)d_in[0];
    const float* X    = (const float*)d_in[1];
    const float* Wm1  = (const float*)d_in[2];
    const float* bm1  = (const float*)d_in[3];
    const float* Wm2  = (const float*)d_in[4];
    const float* bm2  = (const float*)d_in[5];
    const float* Wir  = (const float*)d_in[6];
    const float* bir  = (const float*)d_in[7];
    const float* Wii  = (const float*)d_in[8];
    const float* bii  = (const float*)d_in[9];
    const float* Win  = (const float*)d_in[10];
    const float* bin_ = (const float*)d_in[11];
    const float* Whr  = (const float*)d_in[12];
    const float* Whi  = (const float*)d_in[13];
    const float* Whh  = (const float*)d_in[14];
    const float* Wmr  = (const float*)d_in[15];
    const float* Wmi  = (const float*)d_in[16];
    const float* Wmn  = (const float*)d_in[17];
    const float* Wo1  = (const float*)d_in[18];
    const float* bo1  = (const float*)d_in[19];
    const float* Wo2  = (const float*)d_in[20];
    const float* bo2  = (const float*)d_in[21];
    const float* Wo3  = (const float*)d_in[22];
    const float* bo3  = (const float*)d_in[23];
    const float* lsg  = (const float*)d_in[24];
    float* ws  = (float*)d_ws;
    float* out = (float*)d_out;

    hipLaunchKernelGGL(pre, dim3(NBLK), dim3(256), 0, stream,
                       A, Wm1, bm1, Wm2, Whr, Whi, Whh, Wmr, Wmi, Wmn, Wo1, Wo2, Wo3, ws);

    for (int t = 0; t < TSTEPS; ++t) {
        const float* Pc = ws + ((t & 1) ? OFF_P1 : OFF_P0);
        float*       Pn = ws + ((t & 1) ? OFF_P0 : OFF_P1);
        hipLaunchKernelGGL(step, dim3(NBLK), dim3(256), 0, stream,
                           X, bm2, Wir, bir, Wii, bii, Win, bin_, bm1,
                           bo1, bo2, bo3, lsg, ws, Pc, Pn, out, t);
    }
}

// Round 9
// 437.020 us; speedup vs baseline: 6.3084x; 1.1800x over previous
//
#include <hip/hip_runtime.h>
#include <math.h>

// Problem constants
#define B_ 8
#define N_ 128
#define H_ 64
#define MH_ 128
#define D_ 4
#define TSTEPS 12
#define NBLK 512          // 2 blocks/CU x 256 CU -> all co-resident

typedef __attribute__((ext_vector_type(8))) short bf16x8;
typedef __attribute__((ext_vector_type(4))) float f32x4;
typedef __attribute__((ext_vector_type(4))) unsigned u32x4;
typedef unsigned uint32;

__device__ __forceinline__ float fast_tanh(float x) {
    float t = __builtin_amdgcn_exp2f(x * 2.8853900817779268f);
    return 1.0f - 2.0f * __builtin_amdgcn_rcpf(t + 1.0f);
}
__device__ __forceinline__ float fast_sigmoid(float x) {
    float t = __builtin_amdgcn_exp2f(x * -1.4426950408889634f);
    return __builtin_amdgcn_rcpf(1.0f + t);
}
__device__ __forceinline__ unsigned short f2bf(float x) {
    unsigned u = __builtin_bit_cast(unsigned, x);
    u += 0x7fffu + ((u >> 16) & 1u);   // RNE
    return (unsigned short)(u >> 16);
}

// ---------------- workspace layout (uint32 units) ----------------
// P transported as packed bf16 pairs, double-buffered, via agent-scope (sc1,
// L2-bypassing) relaxed atomics. Everything else is block-local (LDS) or
// read-only (stays warm in each XCD's L2 for the whole single dispatch).
constexpr int PB0u  = 0;              // [8][128][64] uints
constexpr int PB1u  = PB0u + 65536;
constexpr int CTRLu = PB1u + 65536;   // cnt[8] @ stride 16; SSE @ +128; DONE @ +129
constexpr int CTRL_BYTES = (8 * 16 + 2) * 4;

__global__ __launch_bounds__(512, 4) void fused(
    const float* __restrict__ A, const float* __restrict__ X,
    const float* __restrict__ Wm1, const float* __restrict__ bm1,
    const float* __restrict__ Wm2, const float* __restrict__ bm2,
    const float* __restrict__ Wir, const float* __restrict__ bir,
    const float* __restrict__ Wii, const float* __restrict__ bii,
    const float* __restrict__ Win, const float* __restrict__ bin_,
    const float* __restrict__ Whr, const float* __restrict__ Whi, const float* __restrict__ Whh,
    const float* __restrict__ Wmr, const float* __restrict__ Wmi, const float* __restrict__ Wmn,
    const float* __restrict__ Wo1, const float* __restrict__ bo1,
    const float* __restrict__ Wo2, const float* __restrict__ bo2,
    const float* __restrict__ Wo3, const float* __restrict__ bo3,
    const float* __restrict__ lsg,
    uint32* wsU, float* __restrict__ out)
{
    __shared__ __align__(16) uint32 pLds[8192];          // 32 KB: P[b] bf16, XOR-swizzled
    __shared__ __align__(16) unsigned short wm2f[8192];  // 16 KB: Wm2 MFMA B-fragments
    __shared__ float Qj[2][128], apRow[2][128], rs[128];
    __shared__ float aggbuf[2][4][64];                   // also reused for rowsum partials
    __shared__ float sAgg[2][64], sAm[2][192];
    __shared__ float sH[2][64], sHn[2][64], sHP[2][192];
    __shared__ float sT1[2][64], sT2[2][64], sPn[2][128];
    __shared__ float sX[2][4], sTgt[2][4], sSq[2][4], sseb[2];

    const int bid = blockIdx.x, tid = threadIdx.x;
    const int b = bid >> 6;                 // batch
    const int j0 = (bid & 63) << 1;         // this block owns rows j0, j0+1
    const int jj = tid >> 8, tidj = tid & 255;
    const int jrow = j0 + jj;
    const int lane = tid & 63;
    const int wvj = (tid >> 6) & 3;         // wave index within the j-half
    const int l15 = lane & 15, g = lane >> 4;
    const int myI0 = wvj * 32;              // i-window base for this wave

    int*   cnt   = (int*)(wsU + CTRLu) + (b << 4);
    float* sseG  = (float*)(wsU + CTRLu + 128);
    int*   doneG = (int*)(wsU + CTRLu + 129);
    const float* Ab = A + b * 16384;

    // ================= init (fully block-local) =================
    {   // rowsum_i = sum_j sigmoid(0.5(A[i,j]+A[j,i])), j != i  (4-way split over j)
        int i = tid & 127, q = tid >> 7;
        float part = 0.f;
        int jlo = q * 32;
        #pragma unroll 8
        for (int j2 = jlo; j2 < jlo + 32; ++j2) {
            if (j2 != i)
                part += fast_sigmoid(0.5f * (Ab[i * 128 + j2] + Ab[j2 * 128 + i]));
        }
        ((float*)aggbuf)[q * 128 + i] = part;
    }
    __syncthreads();
    if (tid < 128) {
        const float* f = (const float*)aggbuf;
        rs[tid] = f[tid] + f[128 + tid] + f[256 + tid] + f[384 + tid] + 1e-6f;
    }
    __syncthreads();
    if (tid < 256) {    // apRow[h][i] = s(i, j0+h) / rowsum_i
        int i = tid & 127, h = tid >> 7, jc = j0 + h;
        float s = (i == jc) ? 0.f
                : fast_sigmoid(0.5f * (Ab[i * 128 + jc] + Ab[jc * 128 + i]));
        apRow[h][i] = s / rs[i];
    }
    for (int idx = tid; idx < 8192; idx += 512) {   // pack Wm2 -> bf16 B-fragments
        int kt = idx >> 11, nt = (idx >> 9) & 3, ln = (idx >> 3) & 63, e = idx & 7;
        int k = kt * 32 + (ln >> 4) * 8 + e, n = nt * 16 + (ln & 15);
        wm2f[idx] = f2bf(Wm2[k * 64 + n]);
    }
    for (int idx = tid; idx < 8192; idx += 512) {   // P(0) = bm1 (h0 = 0)
        int row = idx >> 6, cw = idx & 63;
        uint32 u = (uint32)f2bf(bm1[2 * cw]) | ((uint32)f2bf(bm1[2 * cw + 1]) << 16);
        pLds[idx ^ ((row & 7) << 2)] = u;
    }
    if (tidj < 128) Qj[jj][tidj] = 0.f;
    if (tidj < 64)  sH[jj][tidj] = 0.f;
    if (tidj < 192) sHP[jj][tidj] = 0.f;
    if (tid < 2) sseb[tid] = 0.f;
    __syncthreads();

    // ================= time loop =================
    for (int t = 0; t < TSTEPS; ++t) {
        if (t > 0) {
            // wait for all 64 writer-blocks of batch b to publish P(t)
            if (tid == 0) {
                const int target = 64 * t;
                int guard = 0;
                while (__hip_atomic_load(cnt, __ATOMIC_RELAXED, __HIP_MEMORY_SCOPE_AGENT) < target
                       && guard < (1 << 20)) {
                    __builtin_amdgcn_s_sleep(2);
                    ++guard;
                }
            }
            __syncthreads();
            // stage P[b] (bf16 pairs) L3 -> LDS, XOR-swizzled
            uint32* src = wsU + ((t & 1) ? PB1u : PB0u) + b * 8192;
            for (int idx = tid; idx < 8192; idx += 512) {
                int row = idx >> 6;
                uint32 u = __hip_atomic_load(src + idx, __ATOMIC_RELAXED, __HIP_MEMORY_SCOPE_AGENT);
                pLds[idx ^ ((row & 7) << 2)] = u;
            }
            __syncthreads();
        }

        // ===== phase A: msg = tanh(tanh(P_i + Q_j) @ Wm2 + bm2), A-weighted agg =====
        f32x4 acc[2][4];
        #pragma unroll
        for (int mt = 0; mt < 2; ++mt)
            #pragma unroll
            for (int nt = 0; nt < 4; ++nt) {
                f32x4 z = {0.f, 0.f, 0.f, 0.f};
                acc[mt][nt] = z;
            }
        #pragma unroll
        for (int kt = 0; kt < 4; ++kt) {
            int k0 = kt * 32 + g * 8;
            bf16x8 bf[4];
            #pragma unroll
            for (int nt = 0; nt < 4; ++nt)
                bf[nt] = *(const bf16x8*)&wm2f[((kt * 4 + nt) * 64 + lane) << 3];
            f32x4 qa = *(const f32x4*)&Qj[jj][k0];
            f32x4 qb = *(const f32x4*)&Qj[jj][k0 + 4];
            bf16x8 af[2];
            #pragma unroll
            for (int mt = 0; mt < 2; ++mt) {
                int row = myI0 + mt * 16 + l15;
                int ub = (row * 64 + kt * 16 + g * 4) ^ ((row & 7) << 2);
                u32x4 pv = *(const u32x4*)&pLds[ub];
                float pe[8];
                #pragma unroll
                for (int c = 0; c < 4; ++c) {
                    pe[2 * c]     = __builtin_bit_cast(float, pv[c] << 16);
                    pe[2 * c + 1] = __builtin_bit_cast(float, pv[c] & 0xFFFF0000u);
                }
                #pragma unroll
                for (int e = 0; e < 4; ++e) {
                    af[mt][e]     = (short)f2bf(fast_tanh(pe[e] + qa[e]));
                    af[mt][4 + e] = (short)f2bf(fast_tanh(pe[4 + e] + qb[e]));
                }
            }
            #pragma unroll
            for (int mt = 0; mt < 2; ++mt)
                #pragma unroll
                for (int nt = 0; nt < 4; ++nt)
                    acc[mt][nt] = __builtin_amdgcn_mfma_f32_16x16x32_bf16(af[mt], bf[nt], acc[mt][nt], 0, 0, 0);
        }
        {
            float bmv[4];
            #pragma unroll
            for (int nt = 0; nt < 4; ++nt) bmv[nt] = bm2[nt * 16 + l15];
            float pagg[4] = {0.f, 0.f, 0.f, 0.f};
            #pragma unroll
            for (int mt = 0; mt < 2; ++mt) {
                float w[4];
                #pragma unroll
                for (int v = 0; v < 4; ++v) w[v] = apRow[jj][myI0 + mt * 16 + g * 4 + v];
                #pragma unroll
                for (int nt = 0; nt < 4; ++nt)
                    #pragma unroll
                    for (int v = 0; v < 4; ++v)
                        pagg[nt] += w[v] * fast_tanh(acc[mt][nt][v] + bmv[nt]);
            }
            #pragma unroll
            for (int nt = 0; nt < 4; ++nt) {
                pagg[nt] += __shfl_xor(pagg[nt], 16);
                pagg[nt] += __shfl_xor(pagg[nt], 32);
            }
            if (lane < 16)
                #pragma unroll
                for (int nt = 0; nt < 4; ++nt) aggbuf[jj][wvj][nt * 16 + lane] = pagg[nt];
        }
        __syncthreads();
        if (tidj < 64)
            sAgg[jj][tidj] = aggbuf[jj][0][tidj] + aggbuf[jj][1][tidj]
                           + aggbuf[jj][2][tidj] + aggbuf[jj][3][tidj];
        if (tidj < 4) {
            sX[jj][tidj]   = X[((b * 13 + t) * 128 + jrow) * 4 + tidj];
            sTgt[jj][tidj] = X[((b * 13 + t + 1) * 128 + jrow) * 4 + tidj];
        }
        __syncthreads();

        // ===== phase B (row-local; raw weights, L2-warm, coalesced per instr) =====
        if (tidj < 192) {   // am = agg @ [Wmr|Wmi|Wmn]
            const float* W = (tidj < 64) ? Wmr : (tidj < 128) ? Wmi : Wmn;
            int o = tidj & 63;
            float a = 0.f;
            #pragma unroll 8
            for (int k = 0; k < 64; ++k) a += sAgg[jj][k] * W[k * 64 + o];
            sAm[jj][tidj] = a;
        }
        __syncthreads();
        if (tidj < 64) {    // GRU gates
            int o = tidj;
            float xr = bir[o], xi = bii[o], xn = bin_[o];
            #pragma unroll
            for (int d = 0; d < 4; ++d) {
                float xv = sX[jj][d];
                xr += xv * Wir[d * 64 + o];
                xi += xv * Wii[d * 64 + o];
                xn += xv * Win[d * 64 + o];
            }
            float rr = fast_sigmoid(xr + sHP[jj][o]       + sAm[jj][o]);
            float ig = fast_sigmoid(xi + sHP[jj][64 + o]  + sAm[jj][64 + o]);
            float nn = fast_tanh  (xn + rr * sHP[jj][128 + o] + sAm[jj][128 + o]);
            float hn = (1.0f - ig) * nn + ig * sH[jj][o];
            sHn[jj][o] = hn;
            sH[jj][o]  = hn;
        }
        __syncthreads();

        if (t < TSTEPS - 1) {   // next-step projections
            {
                int o = tidj;
                if (o < 128) {          // P' = h @ Wm1_top + bm1
                    float a = bm1[o];
                    #pragma unroll 8
                    for (int k = 0; k < 64; ++k) a += sHn[jj][k] * Wm1[k * 128 + o];
                    sPn[jj][o] = a;
                } else {                // Q' = h @ Wm1_bottom
                    int oo = o - 128;
                    float a = 0.f;
                    #pragma unroll 8
                    for (int k = 0; k < 64; ++k) a += sHn[jj][k] * Wm1[(64 + k) * 128 + oo];
                    Qj[jj][oo] = a;
                }
            }
            if (tidj < 192) {           // HP' = h @ [Whr|Whi|Whh]
                const float* W = (tidj < 64) ? Whr : (tidj < 128) ? Whi : Whh;
                int o = tidj & 63;
                float a = 0.f;
                #pragma unroll 8
                for (int k = 0; k < 64; ++k) a += sHn[jj][k] * W[k * 64 + o];
                sHP[jj][tidj] = a;
            }
            __syncthreads();
            if (tidj < 64) {            // publish P' row (bf16 pairs, L2-bypass)
                uint32 u = (uint32)f2bf(sPn[jj][2 * tidj])
                         | ((uint32)f2bf(sPn[jj][2 * tidj + 1]) << 16);
                uint32* dst = wsU + ((t & 1) ? PB0u : PB1u) + b * 8192 + jrow * 64 + tidj;
                __hip_atomic_store(dst, u, __ATOMIC_RELAXED, __HIP_MEMORY_SCOPE_AGENT);
            }
        }

        // output MLP
        if (tidj < 64) {
            float a = bo1[tidj];
            #pragma unroll 8
            for (int k = 0; k < 64; ++k) a += sHn[jj][k] * Wo1[k * 64 + tidj];
            sT1[jj][tidj] = fmaxf(a, 0.f);
        }
        __syncthreads();
        if (tidj < 64) {
            float a = bo2[tidj];
            #pragma unroll 8
            for (int k = 0; k < 64; ++k) a += sT1[jj][k] * Wo2[k * 64 + tidj];
            sT2[jj][tidj] = fmaxf(a, 0.f);
        }
        __syncthreads();
        if (tidj < 4) {
            float a = 0.f;
            #pragma unroll 8
            for (int k = 0; k < 64; ++k) a += sT2[jj][k] * Wo3[k * 4 + tidj];
            float p = sX[jj][tidj] + a + bo3[tidj];
            out[((b * TSTEPS + t) * 128 + jrow) * 4 + tidj] = p;
            float df = sTgt[jj][tidj] - p;
            sSq[jj][tidj] = df * df;
        }
        __syncthreads();
        if (tidj == 0)
            sseb[jj] += sSq[jj][0] + sSq[jj][1] + sSq[jj][2] + sSq[jj][3];
        __syncthreads();   // drains the P' sc1 stores (vmcnt) before the counter add
        if (t < TSTEPS - 1 && tid == 0)
            __hip_atomic_fetch_add(cnt, 1, __ATOMIC_RELAXED, __HIP_MEMORY_SCOPE_AGENT);
    }

    // ================= finalize loglik (last-arriver) =================
    if (tid == 0) atomicAdd(sseG, sseb[0] + sseb[1]);
    __syncthreads();   // drain the SSE atomic before DONE
    if (tid == 0) {
        int prev = __hip_atomic_fetch_add(doneG, 1, __ATOMIC_RELAXED, __HIP_MEMORY_SCOPE_AGENT);
        if (prev == NBLK - 1) {
            float sse = __hip_atomic_load(sseG, __ATOMIC_RELAXED, __HIP_MEMORY_SCOPE_AGENT);
            float ls = lsg[0];
            float sigma = fminf(fmaxf(expf(ls), 1e-4f), 10.0f);
            float c = 0.5f * 4096.0f * logf(2.0f * 3.14159265358979323846f * sigma * sigma);
            float inv2s2 = 1.0f / (2.0f * sigma * sigma);
            out[B_ * TSTEPS * N_ * D_] = -(12.0f * c + sse * inv2s2);
        }
    }
}

extern "C" void kernel_launch(void* const* d_in, const int* in_sizes, int n_in,
                              void* d_out, int out_size, void* d_ws, size_t ws_size,
                              hipStream_t stream)
{
    const float* A    = (const float*)d_in[0];
    const float* X    = (const float*)d_in[1];
    const float* Wm1  = (const float*)d_in[2];
    const float* bm1  = (const float*)d_in[3];
    const float* Wm2  = (const float*)d_in[4];
    const float* bm2  = (const float*)d_in[5];
    const float* Wir  = (const float*)d_in[6];
    const float* bir  = (const float*)d_in[7];
    const float* Wii  = (const float*)d_in[8];
    const float* bii  = (const float*)d_in[9];
    const float* Win  = (const float*)d_in[10];
    const float* bin_ = (const float*)d_in[11];
    const float* Whr  = (const float*)d_in[12];
    const float* Whi  = (const float*)d_in[13];
    const float* Whh  = (const float*)d_in[14];
    const float* Wmr  = (const float*)d_in[15];
    const float* Wmi  = (const float*)d_in[16];
    const float* Wmn  = (const float*)d_in[17];
    const float* Wo1  = (const float*)d_in[18];
    const float* bo1  = (const float*)d_in[19];
    const float* Wo2  = (const float*)d_in[20];
    const float* bo2  = (const float*)d_in[21];
    const float* Wo3  = (const float*)d_in[22];
    const float* bo3  = (const float*)d_in[23];
    const float* lsg  = (const float*)d_in[24];
    uint32* wsU = (uint32*)d_ws;
    float* out = (float*)d_out;

    // zero counters / SSE / DONE each call (graph-replay safe)
    hipMemsetAsync((char*)d_ws + (size_t)CTRLu * 4, 0, CTRL_BYTES, stream);

    hipLaunchKernelGGL(fused, dim3(NBLK), dim3(512), 0, stream,
                       A, X, Wm1, bm1, Wm2, bm2, Wir, bir, Wii, bii, Win, bin_,
                       Whr, Whi, Whh, Wmr, Wmi, Wmn, Wo1, bo1, Wo2, bo2, Wo3, bo3,
                       lsg, wsU, out);
}

// Round 10
// 267.311 us; speedup vs baseline: 10.3134x; 1.6349x over previous
//
#include <hip/hip_runtime.h>
#include <math.h>

// Problem constants
#define B_ 8
#define N_ 128
#define H_ 64
#define MH_ 128
#define D_ 4
#define TSTEPS 12
#define NBLK 512          // 2 blocks/CU x 256 CU -> all co-resident

typedef __attribute__((ext_vector_type(8))) short bf16x8;
typedef __attribute__((ext_vector_type(4))) float f32x4;
typedef __attribute__((ext_vector_type(4))) unsigned u32x4;
typedef unsigned uint32;
typedef unsigned long long ull;

__device__ __forceinline__ float fast_tanh(float x) {
    float t = __builtin_amdgcn_exp2f(x * 2.8853900817779268f);
    return 1.0f - 2.0f * __builtin_amdgcn_rcpf(t + 1.0f);
}
__device__ __forceinline__ float fast_sigmoid(float x) {
    float t = __builtin_amdgcn_exp2f(x * -1.4426950408889634f);
    return __builtin_amdgcn_rcpf(1.0f + t);
}
__device__ __forceinline__ unsigned short f2bf(float x) {
    unsigned u = __builtin_bit_cast(unsigned, x);
    u += 0x7fffu + ((u >> 16) & 1u);   // RNE
    return (unsigned short)(u >> 16);
}
__device__ __forceinline__ uint32 pack2(float lo, float hi) {
    return (uint32)f2bf(lo) | ((uint32)f2bf(hi) << 16);
}

// ---------------- workspace layout (uint32 units) ----------------
// P(t) for t=0..10 lives in its OWN buffer (no reuse): consumers read each
// address exactly once and never before the producer's write-through lands,
// so plain coalesced loads are guaranteed fresh (no agent fences needed).
// Producer side stays write-through via relaxed agent-scope atomic stores.
constexpr int PB_STRIDE = 65536;              // [8][128][64] uints per step-buffer
constexpr int CTRLu = 11 * PB_STRIDE;         // cnt[8] @ stride 16; SSE @ +128; DONE @ +129
constexpr int CTRL_BYTES = (8 * 16 + 2) * 4;

__global__ __launch_bounds__(512, 4) void fused(
    const float* __restrict__ A, const float* __restrict__ X,
    const float* __restrict__ Wm1, const float* __restrict__ bm1,
    const float* __restrict__ Wm2, const float* __restrict__ bm2,
    const float* __restrict__ Wir, const float* __restrict__ bir,
    const float* __restrict__ Wii, const float* __restrict__ bii,
    const float* __restrict__ Win, const float* __restrict__ bin_,
    const float* __restrict__ Whr, const float* __restrict__ Whi, const float* __restrict__ Whh,
    const float* __restrict__ Wmr, const float* __restrict__ Wmi, const float* __restrict__ Wmn,
    const float* __restrict__ Wo1, const float* __restrict__ bo1,
    const float* __restrict__ Wo2, const float* __restrict__ bo2,
    const float* __restrict__ Wo3, const float* __restrict__ bo3,
    const float* __restrict__ lsg,
    uint32* wsU, float* __restrict__ out)
{
    __shared__ __align__(16) uint32 pLds[8192];          // 32 KB: P[b] bf16, XOR-swizzled
    __shared__ __align__(16) unsigned short wm2f[8192];  // 16 KB: Wm2 MFMA B-fragments
    __shared__ float Qj[2][128], apRow[2][128], rs[128];
    __shared__ float aggbuf[2][4][64];                   // also reused for rowsum partials
    __shared__ float sAgg[2][64], sAm[2][192];
    __shared__ float sH[2][64], sHn[2][64], sHP[2][192];
    __shared__ float sT1[2][64], sT2[2][64], sPn[2][128];
    __shared__ float sX[2][4], sTgt[2][4], sSq[2][4], sseb[2];

    const int bid = blockIdx.x, tid = threadIdx.x;
    const int b = bid >> 6;                 // batch
    const int j0 = (bid & 63) << 1;         // this block owns rows j0, j0+1
    const int jj = tid >> 8, tidj = tid & 255;
    const int jrow = j0 + jj;
    const int lane = tid & 63;
    const int wvj = (tid >> 6) & 3;         // wave index within the j-half
    const int l15 = lane & 15, g = lane >> 4;
    const int myI0 = wvj * 32;              // i-window base for this wave

    int*   cnt   = (int*)(wsU + CTRLu) + (b << 4);
    float* sseG  = (float*)(wsU + CTRLu + 128);
    int*   doneG = (int*)(wsU + CTRLu + 129);
    const float* Ab = A + b * 16384;

    // ================= init (fully block-local) =================
    {   // rowsum_i = sum_j sigmoid(0.5(A[i,j]+A[j,i])), j != i  (4-way split over j)
        int i = tid & 127, q = tid >> 7;
        float part = 0.f;
        int jlo = q * 32;
        #pragma unroll 8
        for (int j2 = jlo; j2 < jlo + 32; ++j2) {
            if (j2 != i)
                part += fast_sigmoid(0.5f * (Ab[i * 128 + j2] + Ab[j2 * 128 + i]));
        }
        ((float*)aggbuf)[q * 128 + i] = part;
    }
    __syncthreads();
    if (tid < 128) {
        const float* f = (const float*)aggbuf;
        rs[tid] = f[tid] + f[128 + tid] + f[256 + tid] + f[384 + tid] + 1e-6f;
    }
    __syncthreads();
    if (tid < 256) {    // apRow[h][i] = s(i, j0+h) / rowsum_i
        int i = tid & 127, h = tid >> 7, jc = j0 + h;
        float s = (i == jc) ? 0.f
                : fast_sigmoid(0.5f * (Ab[i * 128 + jc] + Ab[jc * 128 + i]));
        apRow[h][i] = s / rs[i];
    }
    for (int idx = tid; idx < 8192; idx += 512) {   // pack Wm2 -> bf16 B-fragments
        int kt = idx >> 11, nt = (idx >> 9) & 3, ln = (idx >> 3) & 63, e = idx & 7;
        int k = kt * 32 + (ln >> 4) * 8 + e, n = nt * 16 + (ln & 15);
        wm2f[idx] = f2bf(Wm2[k * 64 + n]);
    }
    for (int idx = tid; idx < 8192; idx += 512) {   // P(0) = bm1 (h0 = 0)
        int row = idx >> 6, cw = idx & 63;
        pLds[idx ^ ((row & 7) << 2)] = pack2(bm1[2 * cw], bm1[2 * cw + 1]);
    }
    if (tidj < 128) Qj[jj][tidj] = 0.f;
    if (tidj < 64)  sH[jj][tidj] = 0.f;
    if (tidj < 192) sHP[jj][tidj] = 0.f;
    if (tid < 2) sseb[tid] = 0.f;
    __syncthreads();

    // ================= time loop =================
    for (int t = 0; t < TSTEPS; ++t) {
        if (t > 0) {
            // wait for all 64 writer-blocks of batch b to publish P(t) into buffer t-1
            if (tid == 0) {
                const int target = 64 * t;
                int guard = 0;
                while (__hip_atomic_load(cnt, __ATOMIC_RELAXED, __HIP_MEMORY_SCOPE_AGENT) < target
                       && guard < (1 << 20)) {
                    __builtin_amdgcn_s_sleep(2);
                    ++guard;
                }
            }
            __syncthreads();
            __builtin_amdgcn_fence(__ATOMIC_ACQUIRE, "workgroup");  // compile-order only
            // stage P[b] -> LDS: coalesced 16B loads (fresh addresses, never cached)
            const uint32* src = wsU + (t - 1) * PB_STRIDE + b * 8192;
            #pragma unroll
            for (int c = 0; c < 4; ++c) {
                int base = c * 2048 + tid * 4;
                u32x4 v = *(const u32x4*)(src + base);
                int row = base >> 6;
                *(u32x4*)&pLds[base ^ ((row & 7) << 2)] = v;
            }
            __syncthreads();
        }

        // ===== phase A: msg = tanh(tanh(P_i + Q_j) @ Wm2 + bm2), A-weighted agg =====
        f32x4 acc[2][4];
        #pragma unroll
        for (int mt = 0; mt < 2; ++mt)
            #pragma unroll
            for (int nt = 0; nt < 4; ++nt) {
                f32x4 z = {0.f, 0.f, 0.f, 0.f};
                acc[mt][nt] = z;
            }
        #pragma unroll
        for (int kt = 0; kt < 4; ++kt) {
            int k0 = kt * 32 + g * 8;
            bf16x8 bf[4];
            #pragma unroll
            for (int nt = 0; nt < 4; ++nt)
                bf[nt] = *(const bf16x8*)&wm2f[((kt * 4 + nt) * 64 + lane) << 3];
            f32x4 qa = *(const f32x4*)&Qj[jj][k0];
            f32x4 qb = *(const f32x4*)&Qj[jj][k0 + 4];
            bf16x8 af[2];
            #pragma unroll
            for (int mt = 0; mt < 2; ++mt) {
                int row = myI0 + mt * 16 + l15;
                int ub = (row * 64 + kt * 16 + g * 4) ^ ((row & 7) << 2);
                u32x4 pv = *(const u32x4*)&pLds[ub];
                float pe[8];
                #pragma unroll
                for (int c = 0; c < 4; ++c) {
                    pe[2 * c]     = __builtin_bit_cast(float, pv[c] << 16);
                    pe[2 * c + 1] = __builtin_bit_cast(float, pv[c] & 0xFFFF0000u);
                }
                #pragma unroll
                for (int e = 0; e < 4; ++e) {
                    af[mt][e]     = (short)f2bf(fast_tanh(pe[e] + qa[e]));
                    af[mt][4 + e] = (short)f2bf(fast_tanh(pe[4 + e] + qb[e]));
                }
            }
            #pragma unroll
            for (int mt = 0; mt < 2; ++mt)
                #pragma unroll
                for (int nt = 0; nt < 4; ++nt)
                    acc[mt][nt] = __builtin_amdgcn_mfma_f32_16x16x32_bf16(af[mt], bf[nt], acc[mt][nt], 0, 0, 0);
        }
        {
            float bmv[4];
            #pragma unroll
            for (int nt = 0; nt < 4; ++nt) bmv[nt] = bm2[nt * 16 + l15];
            float pagg[4] = {0.f, 0.f, 0.f, 0.f};
            #pragma unroll
            for (int mt = 0; mt < 2; ++mt) {
                float w[4];
                #pragma unroll
                for (int v = 0; v < 4; ++v) w[v] = apRow[jj][myI0 + mt * 16 + g * 4 + v];
                #pragma unroll
                for (int nt = 0; nt < 4; ++nt)
                    #pragma unroll
                    for (int v = 0; v < 4; ++v)
                        pagg[nt] += w[v] * fast_tanh(acc[mt][nt][v] + bmv[nt]);
            }
            #pragma unroll
            for (int nt = 0; nt < 4; ++nt) {
                pagg[nt] += __shfl_xor(pagg[nt], 16);
                pagg[nt] += __shfl_xor(pagg[nt], 32);
            }
            if (lane < 16)
                #pragma unroll
                for (int nt = 0; nt < 4; ++nt) aggbuf[jj][wvj][nt * 16 + lane] = pagg[nt];
        }
        __syncthreads();
        if (tidj < 64)
            sAgg[jj][tidj] = aggbuf[jj][0][tidj] + aggbuf[jj][1][tidj]
                           + aggbuf[jj][2][tidj] + aggbuf[jj][3][tidj];
        if (tidj < 4) {
            sX[jj][tidj]   = X[((b * 13 + t) * 128 + jrow) * 4 + tidj];
            sTgt[jj][tidj] = X[((b * 13 + t + 1) * 128 + jrow) * 4 + tidj];
        }
        __syncthreads();

        // ===== phase B (row-local; raw weights, L2-warm across the whole dispatch) =====
        if (tidj < 192) {   // am = agg @ [Wmr|Wmi|Wmn]
            const float* W = (tidj < 64) ? Wmr : (tidj < 128) ? Wmi : Wmn;
            int o = tidj & 63;
            float a = 0.f;
            #pragma unroll 8
            for (int k = 0; k < 64; ++k) a += sAgg[jj][k] * W[k * 64 + o];
            sAm[jj][tidj] = a;
        }
        __syncthreads();
        if (tidj < 64) {    // GRU gates
            int o = tidj;
            float xr = bir[o], xi = bii[o], xn = bin_[o];
            #pragma unroll
            for (int d = 0; d < 4; ++d) {
                float xv = sX[jj][d];
                xr += xv * Wir[d * 64 + o];
                xi += xv * Wii[d * 64 + o];
                xn += xv * Win[d * 64 + o];
            }
            float rr = fast_sigmoid(xr + sHP[jj][o]       + sAm[jj][o]);
            float ig = fast_sigmoid(xi + sHP[jj][64 + o]  + sAm[jj][64 + o]);
            float nn = fast_tanh  (xn + rr * sHP[jj][128 + o] + sAm[jj][128 + o]);
            float hn = (1.0f - ig) * nn + ig * sH[jj][o];
            sHn[jj][o] = hn;
            sH[jj][o]  = hn;
        }
        __syncthreads();

        if (t < TSTEPS - 1) {   // next-step projections, publish P' EARLY
            {
                int o = tidj;
                if (o < 128) {          // P' = h @ Wm1_top + bm1
                    float a = bm1[o];
                    #pragma unroll 8
                    for (int k = 0; k < 64; ++k) a += sHn[jj][k] * Wm1[k * 128 + o];
                    sPn[jj][o] = a;
                } else {                // Q' = h @ Wm1_bottom
                    int oo = o - 128;
                    float a = 0.f;
                    #pragma unroll 8
                    for (int k = 0; k < 64; ++k) a += sHn[jj][k] * Wm1[(64 + k) * 128 + oo];
                    Qj[jj][oo] = a;
                }
            }
            if (tidj < 192) {           // HP' = h @ [Whr|Whi|Whh]
                const float* W = (tidj < 64) ? Whr : (tidj < 128) ? Whi : Whh;
                int o = tidj & 63;
                float a = 0.f;
                #pragma unroll 8
                for (int k = 0; k < 64; ++k) a += sHn[jj][k] * W[k * 64 + o];
                sHP[jj][tidj] = a;
            }
            __syncthreads();
            if (tidj < 32) {            // publish P' row: 8B write-through stores
                ull u = (ull)pack2(sPn[jj][4 * tidj],     sPn[jj][4 * tidj + 1])
                      | ((ull)pack2(sPn[jj][4 * tidj + 2], sPn[jj][4 * tidj + 3]) << 32);
                ull* dst = (ull*)(wsU + t * PB_STRIDE + b * 8192 + jrow * 64) + tidj;
                __hip_atomic_store(dst, u, __ATOMIC_RELAXED, __HIP_MEMORY_SCOPE_AGENT);
            }
            __syncthreads();            // drains publish stores (vmcnt) before signal
            if (tid == 0)
                __hip_atomic_fetch_add(cnt, 1, __ATOMIC_RELAXED, __HIP_MEMORY_SCOPE_AGENT);
        }

        // output MLP (off the inter-step critical path)
        if (tidj < 64) {
            float a = bo1[tidj];
            #pragma unroll 8
            for (int k = 0; k < 64; ++k) a += sHn[jj][k] * Wo1[k * 64 + tidj];
            sT1[jj][tidj] = fmaxf(a, 0.f);
        }
        __syncthreads();
        if (tidj < 64) {
            float a = bo2[tidj];
            #pragma unroll 8
            for (int k = 0; k < 64; ++k) a += sT1[jj][k] * Wo2[k * 64 + tidj];
            sT2[jj][tidj] = fmaxf(a, 0.f);
        }
        __syncthreads();
        if (tidj < 4) {
            float a = 0.f;
            #pragma unroll 8
            for (int k = 0; k < 64; ++k) a += sT2[jj][k] * Wo3[k * 4 + tidj];
            float p = sX[jj][tidj] + a + bo3[tidj];
            out[((b * TSTEPS + t) * 128 + jrow) * 4 + tidj] = p;
            float df = sTgt[jj][tidj] - p;
            sSq[jj][tidj] = df * df;
        }
        __syncthreads();
        if (tidj == 0)
            sseb[jj] += sSq[jj][0] + sSq[jj][1] + sSq[jj][2] + sSq[jj][3];
        __syncthreads();
    }

    // ================= finalize loglik (last-arriver) =================
    if (tid == 0) atomicAdd(sseG, sseb[0] + sseb[1]);
    __syncthreads();   // drain the SSE atomic before DONE
    if (tid == 0) {
        int prev = __hip_atomic_fetch_add(doneG, 1, __ATOMIC_RELAXED, __HIP_MEMORY_SCOPE_AGENT);
        if (prev == NBLK - 1) {
            float sse = __hip_atomic_load(sseG, __ATOMIC_RELAXED, __HIP_MEMORY_SCOPE_AGENT);
            float ls = lsg[0];
            float sigma = fminf(fmaxf(expf(ls), 1e-4f), 10.0f);
            float c = 0.5f * 4096.0f * logf(2.0f * 3.14159265358979323846f * sigma * sigma);
            float inv2s2 = 1.0f / (2.0f * sigma * sigma);
            out[B_ * TSTEPS * N_ * D_] = -(12.0f * c + sse * inv2s2);
        }
    }
}

extern "C" void kernel_launch(void* const* d_in, const int* in_sizes, int n_in,
                              void* d_out, int out_size, void* d_ws, size_t ws_size,
                              hipStream_t stream)
{
    const float* A    = (const float*)d_in[0];
    const float* X    = (const float*)d_in[1];
    const float* Wm1  = (const float*)d_in[2];
    const float* bm1  = (const float*)d_in[3];
    const float* Wm2  = (const float*)d_in[4];
    const float* bm2  = (const float*)d_in[5];
    const float* Wir  = (const float*)d_in[6];
    const float* bir  = (const float*)d_in[7];
    const float* Wii  = (const float*)d_in[8];
    const float* bii  = (const float*)d_in[9];
    const float* Win  = (const float*)d_in[10];
    const float* bin_ = (const float*)d_in[11];
    const float* Whr  = (const float*)d_in[12];
    const float* Whi  = (const float*)d_in[13];
    const float* Whh  = (const float*)d_in[14];
    const float* Wmr  = (const float*)d_in[15];
    const float* Wmi  = (const float*)d_in[16];
    const float* Wmn  = (const float*)d_in[17];
    const float* Wo1  = (const float*)d_in[18];
    const float* bo1  = (const float*)d_in[19];
    const float* Wo2  = (const float*)d_in[20];
    const float* bo2  = (const float*)d_in[21];
    const float* Wo3  = (const float*)d_in[22];
    const float* bo3  = (const float*)d_in[23];
    const float* lsg  = (const float*)d_in[24];
    uint32* wsU = (uint32*)d_ws;
    float* out = (float*)d_out;

    // zero counters / SSE / DONE each call (graph-replay safe)
    hipMemsetAsync((char*)d_ws + (size_t)CTRLu * 4, 0, CTRL_BYTES, stream);

    hipLaunchKernelGGL(fused, dim3(NBLK), dim3(512), 0, stream,
                       A, X, Wm1, bm1, Wm2, bm2, Wir, bir, Wii, bii, Win, bin_,
                       Whr, Whi, Whh, Wmr, Wmi, Wmn, Wo1, bo1, Wo2, bo2, Wo3, bo3,
                       lsg, wsU, out);
}